// Round 1
// baseline (278.150 us; speedup 1.0000x reference)
//
#include <hip/hip_runtime.h>
#include <cstdint>
#include <cstddef>

#define B_ 8
#define T_ 4096
#define C_ 256
#define NC_ 64
#define L_ (T_ / NC_)   // 64 steps per chunk
#define M_ (B_ * T_)    // 32768 rows

typedef float f32x4 __attribute__((ext_vector_type(4)));
typedef short bf16x8 __attribute__((ext_vector_type(8)));

__device__ __forceinline__ unsigned short f2b(float f) {
    unsigned int u = __float_as_uint(f);
    u += 0x7fffu + ((u >> 16) & 1u);   // round-to-nearest-even
    return (unsigned short)(u >> 16);
}
__device__ __forceinline__ float b2f(unsigned short h) {
    return __uint_as_float(((unsigned int)h) << 16);
}

// ---------------- f32 -> bf16 converts ----------------
__global__ __launch_bounds__(256) void cvt_x(const float* __restrict__ in,
                                             unsigned short* __restrict__ out) {
    size_t i = ((size_t)blockIdx.x * 256 + threadIdx.x) * 4;
    float4 v = *(const float4*)(in + i);
    ushort4 o = make_ushort4(f2b(v.x), f2b(v.y), f2b(v.z), f2b(v.w));
    *(ushort4*)(out + i) = o;
}

__global__ __launch_bounds__(256) void cvt_w(const float* __restrict__ w0, const float* __restrict__ w1,
                                             const float* __restrict__ w2, const float* __restrict__ w3,
                                             unsigned short* __restrict__ o0, unsigned short* __restrict__ o1,
                                             unsigned short* __restrict__ o2, unsigned short* __restrict__ o3) {
    const float* in; unsigned short* out;
    switch (blockIdx.y) {
        case 0: in = w0; out = o0; break;
        case 1: in = w1; out = o1; break;
        case 2: in = w2; out = o2; break;
        default: in = w3; out = o3; break;
    }
    size_t i = ((size_t)blockIdx.x * 256 + threadIdx.x) * 4;
    float4 v = *(const float4*)(in + i);
    *(ushort4*)(out + i) = make_ushort4(f2b(v.x), f2b(v.y), f2b(v.z), f2b(v.w));
}

// ---------------- GEMM: O[m,n] = sum_k A[m,k] * W[n,k]  (A,W bf16, acc f32) ---
// MODE 0: store f32.  MODE 1: store sigmoid() as bf16.
// A-frag (16x16x32):  A[m = lane&15][k = (lane>>4)*8 + j], j=0..7 contiguous
// B-frag:             B[k][n] with n = lane&15, k = (lane>>4)*8 + j  == W[n][k] rows
// D:                  D[row = (lane>>4)*4 + i][col = lane&15]
template <int MODE>
__global__ __launch_bounds__(256) void gemm_bt(const unsigned short* __restrict__ A,
                                               const unsigned short* __restrict__ W,
                                               float* __restrict__ Of,
                                               unsigned short* __restrict__ Ob) {
    const int wave = threadIdx.x >> 6, lane = threadIdx.x & 63;
    const int quad = lane >> 4, l16 = lane & 15;
    const int m0 = blockIdx.x * 64 + wave * 16;

    const unsigned short* Arow = A + (size_t)(m0 + l16) * C_ + quad * 8;
    bf16x8 af[8];
#pragma unroll
    for (int kc = 0; kc < 8; ++kc) af[kc] = *(const bf16x8*)(Arow + kc * 32);

    for (int nt = 0; nt < 16; ++nt) {
        const unsigned short* Wrow = W + (size_t)(nt * 16 + l16) * C_ + quad * 8;
        f32x4 acc = {0.f, 0.f, 0.f, 0.f};
#pragma unroll
        for (int kc = 0; kc < 8; ++kc) {
            bf16x8 bf = *(const bf16x8*)(Wrow + kc * 32);
            acc = __builtin_amdgcn_mfma_f32_16x16x32_bf16(af[kc], bf, acc, 0, 0, 0);
        }
        const int col = nt * 16 + l16;
#pragma unroll
        for (int i = 0; i < 4; ++i) {
            const int row = m0 + quad * 4 + i;
            if (MODE == 0) {
                Of[(size_t)row * C_ + col] = acc[i];
            } else {
                float s = 1.f / (1.f + __expf(-acc[i]));
                Ob[(size_t)row * C_ + col] = f2b(s);
            }
        }
    }
}

// ---------------- WKV pass 1: chunk-local states from zero init ----------------
__global__ __launch_bounds__(256) void wkv_pass1(const float* __restrict__ k,
                                                 const float* __restrict__ v,
                                                 const float* __restrict__ decay,
                                                 float* __restrict__ sp, float* __restrict__ sq,
                                                 float* __restrict__ so) {
    const int c = threadIdx.x, chunk = blockIdx.x, b = blockIdx.y;
    const float w = decay[c] * (1.0f / T_);
    size_t base = ((size_t)b * T_ + (size_t)chunk * L_) * C_ + c;
    float p = 0.f, q = 0.f, o = -1e38f;
    for (int t = 0; t < L_; t += 8) {
        float kk[8], vv[8];
#pragma unroll
        for (int j = 0; j < 8; ++j) {
            kk[j] = k[base + (size_t)(t + j) * C_];
            vv[j] = v[base + (size_t)(t + j) * C_];
        }
#pragma unroll
        for (int j = 0; j < 8; ++j) {
            float wo = w + o;
            float no = fmaxf(wo, kk[j]);
            float a2 = __expf(wo - no), b2 = __expf(kk[j] - no);
            p = a2 * p + b2 * vv[j];
            q = a2 * q + b2;
            o = no;
        }
    }
    size_t idx = ((size_t)b * NC_ + chunk) * C_ + c;
    sp[idx] = p; sq[idx] = q; so[idx] = o;
}

// ---------------- WKV combine: sequential over chunks, emit init states --------
__global__ __launch_bounds__(256) void wkv_combine(const float* __restrict__ decay,
                                                   const float* __restrict__ sp,
                                                   const float* __restrict__ sq,
                                                   const float* __restrict__ so,
                                                   float* __restrict__ pi, float* __restrict__ qi,
                                                   float* __restrict__ oi) {
    const int c = threadIdx.x, b = blockIdx.x;
    const float wL = decay[c] * (1.0f / T_) * (float)L_;
    float p = 0.f, q = 0.f, o = -1e38f;
    for (int ch = 0; ch < NC_; ch += 8) {
        float lp[8], lq[8], lo[8];
#pragma unroll
        for (int j = 0; j < 8; ++j) {
            size_t idx = ((size_t)b * NC_ + ch + j) * C_ + c;
            lp[j] = sp[idx]; lq[j] = sq[idx]; lo[j] = so[idx];
        }
#pragma unroll
        for (int j = 0; j < 8; ++j) {
            size_t idx = ((size_t)b * NC_ + ch + j) * C_ + c;
            pi[idx] = p; qi[idx] = q; oi[idx] = o;   // state BEFORE this chunk
            float ow = o + wL;
            float no = fmaxf(ow, lo[j]);
            float ea = __expf(ow - no), eb = __expf(lo[j] - no);
            p = ea * p + eb * lp[j];
            q = ea * q + eb * lq[j];
            o = no;
        }
    }
}

// ---------------- WKV pass 2: emit y (overwrites k buffer) ---------------------
__global__ __launch_bounds__(256) void wkv_pass2(float* __restrict__ k,   // in: k, out: y
                                                 const float* __restrict__ v,
                                                 const float* __restrict__ decay,
                                                 const float* __restrict__ first,
                                                 const float* __restrict__ pi,
                                                 const float* __restrict__ qi,
                                                 const float* __restrict__ oi) {
    const int c = threadIdx.x, chunk = blockIdx.x, b = blockIdx.y;
    const float w = decay[c] * (1.0f / T_);
    const float u = first[c] * (1.0f / T_);
    size_t sidx = ((size_t)b * NC_ + chunk) * C_ + c;
    float p = pi[sidx], q = qi[sidx], o = oi[sidx];
    size_t base = ((size_t)b * T_ + (size_t)chunk * L_) * C_ + c;
    for (int t = 0; t < L_; t += 8) {
        float kk[8], vv[8], yy[8];
#pragma unroll
        for (int j = 0; j < 8; ++j) {
            kk[j] = k[base + (size_t)(t + j) * C_];
            vv[j] = v[base + (size_t)(t + j) * C_];
        }
#pragma unroll
        for (int j = 0; j < 8; ++j) {
            float uk = u + kk[j];
            float no = fmaxf(o, uk);
            float a = __expf(o - no), bb = __expf(uk - no);
            yy[j] = (a * p + bb * vv[j]) / (a * q + bb);
            float wo = w + o;
            float no2 = fmaxf(wo, kk[j]);
            float a2 = __expf(wo - no2), b2 = __expf(kk[j] - no2);
            p = a2 * p + b2 * vv[j];
            q = a2 * q + b2;
            o = no2;
        }
#pragma unroll
        for (int j = 0; j < 8; ++j) k[base + (size_t)(t + j) * C_] = yy[j];
    }
}

// ---------------- LayerNorm(C) + sigmoid-gate, emit bf16 z ---------------------
__global__ __launch_bounds__(256) void ln_gate(const float* __restrict__ y,
                                               const unsigned short* __restrict__ sr,
                                               const float* __restrict__ lw,
                                               const float* __restrict__ lb,
                                               unsigned short* __restrict__ z) {
    const int wave = threadIdx.x >> 6, lane = threadIdx.x & 63;
    const int row = blockIdx.x * 4 + wave;
    const float* yr = y + (size_t)row * C_;
    float4 vv = *(const float4*)(yr + lane * 4);
    float s = vv.x + vv.y + vv.z + vv.w;
#pragma unroll
    for (int m = 1; m < 64; m <<= 1) s += __shfl_xor(s, m, 64);
    float mu = s * (1.f / C_);
    float d0 = vv.x - mu, d1 = vv.y - mu, d2 = vv.z - mu, d3 = vv.w - mu;
    float ss = d0 * d0 + d1 * d1 + d2 * d2 + d3 * d3;
#pragma unroll
    for (int m = 1; m < 64; m <<= 1) ss += __shfl_xor(ss, m, 64);
    float rstd = rsqrtf(ss * (1.f / C_) + 1e-5f);
    float4 w4 = *(const float4*)(lw + lane * 4);
    float4 b4 = *(const float4*)(lb + lane * 4);
    ushort4 s4 = *(const ushort4*)(sr + (size_t)row * C_ + lane * 4);
    float z0 = (d0 * rstd * w4.x + b4.x) * b2f(s4.x);
    float z1 = (d1 * rstd * w4.y + b4.y) * b2f(s4.y);
    float z2 = (d2 * rstd * w4.z + b4.z) * b2f(s4.z);
    float z3 = (d3 * rstd * w4.w + b4.w) * b2f(s4.w);
    *(ushort4*)(z + (size_t)row * C_ + lane * 4) =
        make_ushort4(f2b(z0), f2b(z1), f2b(z2), f2b(z3));
}

extern "C" void kernel_launch(void* const* d_in, const int* in_sizes, int n_in,
                              void* d_out, int out_size, void* d_ws, size_t ws_size,
                              hipStream_t stream) {
    const float* x     = (const float*)d_in[0];
    const float* Wk    = (const float*)d_in[1];
    const float* Wv    = (const float*)d_in[2];
    const float* Wr    = (const float*)d_in[3];
    const float* Wo    = (const float*)d_in[4];
    const float* decay = (const float*)d_in[5];
    const float* first = (const float*)d_in[6];
    const float* lnw   = (const float*)d_in[7];
    const float* lnb   = (const float*)d_in[8];
    float* out = (float*)d_out;

    char* ws = (char*)d_ws;
    const size_t NE = (size_t)M_ * C_;              // 8388608
    unsigned short* xb  = (unsigned short*)ws; ws += NE * 2;
    unsigned short* wkb = (unsigned short*)ws; ws += 65536 * 2;
    unsigned short* wvb = (unsigned short*)ws; ws += 65536 * 2;
    unsigned short* wrb = (unsigned short*)ws; ws += 65536 * 2;
    unsigned short* wob = (unsigned short*)ws; ws += 65536 * 2;
    float* kbuf = (float*)ws; ws += NE * 4;         // k, later y
    float* vbuf = (float*)ws; ws += NE * 4;
    unsigned short* srb = (unsigned short*)ws; ws += NE * 2;
    unsigned short* zb  = (unsigned short*)ws; ws += NE * 2;
    const size_t SE = (size_t)B_ * NC_ * C_;        // 131072
    float* sp = (float*)ws; ws += SE * 4;
    float* sq = (float*)ws; ws += SE * 4;
    float* so = (float*)ws; ws += SE * 4;
    float* pi = (float*)ws; ws += SE * 4;
    float* qi = (float*)ws; ws += SE * 4;
    float* oi = (float*)ws; ws += SE * 4;

    cvt_x<<<8192, 256, 0, stream>>>(x, xb);
    cvt_w<<<dim3(64, 4), 256, 0, stream>>>(Wk, Wv, Wr, Wo, wkb, wvb, wrb, wob);

    gemm_bt<0><<<M_ / 64, 256, 0, stream>>>(xb, wkb, kbuf, nullptr);
    gemm_bt<0><<<M_ / 64, 256, 0, stream>>>(xb, wvb, vbuf, nullptr);
    gemm_bt<1><<<M_ / 64, 256, 0, stream>>>(xb, wrb, nullptr, srb);

    wkv_pass1<<<dim3(NC_, B_), 256, 0, stream>>>(kbuf, vbuf, decay, sp, sq, so);
    wkv_combine<<<B_, 256, 0, stream>>>(decay, sp, sq, so, pi, qi, oi);
    wkv_pass2<<<dim3(NC_, B_), 256, 0, stream>>>(kbuf, vbuf, decay, first, pi, qi, oi);

    ln_gate<<<M_ / 4, 256, 0, stream>>>(kbuf, srb, lnw, lnb, zb);
    gemm_bt<0><<<M_ / 64, 256, 0, stream>>>(zb, wob, out, nullptr);
}

// Round 2
// 238.614 us; speedup vs baseline: 1.1657x; 1.1657x over previous
//
#include <hip/hip_runtime.h>
#include <cstdint>
#include <cstddef>

#define B_ 8
#define T_ 4096
#define C_ 256
#define NC_ 64
#define L_ (T_ / NC_)   // 64 steps per chunk
#define M_ (B_ * T_)    // 32768 rows

typedef float f32x4 __attribute__((ext_vector_type(4)));
typedef short bf16x8 __attribute__((ext_vector_type(8)));

__device__ __forceinline__ unsigned short f2b(float f) {
    unsigned int u = __float_as_uint(f);
    u += 0x7fffu + ((u >> 16) & 1u);   // round-to-nearest-even
    return (unsigned short)(u >> 16);
}
__device__ __forceinline__ float b2f(unsigned short h) {
    return __uint_as_float(((unsigned int)h) << 16);
}

// ---------------- f32 -> bf16 weight converts (4 × 256×256, tiny) -------------
__global__ __launch_bounds__(256) void cvt_w(const float* __restrict__ w0, const float* __restrict__ w1,
                                             const float* __restrict__ w2, const float* __restrict__ w3,
                                             unsigned short* __restrict__ o0, unsigned short* __restrict__ o1,
                                             unsigned short* __restrict__ o2, unsigned short* __restrict__ o3) {
    const float* in; unsigned short* out;
    switch (blockIdx.y) {
        case 0: in = w0; out = o0; break;
        case 1: in = w1; out = o1; break;
        case 2: in = w2; out = o2; break;
        default: in = w3; out = o3; break;
    }
    size_t i = ((size_t)blockIdx.x * 256 + threadIdx.x) * 4;
    float4 v = *(const float4*)(in + i);
    *(ushort4*)(out + i) = make_ushort4(f2b(v.x), f2b(v.y), f2b(v.z), f2b(v.w));
}

// ---------------- Fused QKV GEMM --------------------------------------------
// O[m,n] = sum_k x[m,k] * W[n,k].  x read as f32, converted to bf16 in-reg.
// Block: 64 rows × 256 cols. Wave w: all 64 rows × cols [w*64, w*64+64).
// A-frags held in registers (4 m-tiles × 8 kc), reused for all 3 matrices.
// k, v stored f32; r stored as sigmoid(r) bf16.
__global__ __launch_bounds__(256, 2) void gemm_qkv(const float* __restrict__ x,
                                                   const unsigned short* __restrict__ wk,
                                                   const unsigned short* __restrict__ wv,
                                                   const unsigned short* __restrict__ wr,
                                                   float* __restrict__ kout,
                                                   float* __restrict__ vout,
                                                   unsigned short* __restrict__ srout) {
    const int wave = threadIdx.x >> 6, lane = threadIdx.x & 63;
    const int quad = lane >> 4, l16 = lane & 15;
    const int m0 = blockIdx.x * 64;
    const int n0 = wave * 64;

    bf16x8 af[4][8];
#pragma unroll
    for (int mt = 0; mt < 4; ++mt) {
        const float* Ar = x + (size_t)(m0 + mt * 16 + l16) * C_ + quad * 8;
#pragma unroll
        for (int kc = 0; kc < 8; ++kc) {
            float4 a0 = *(const float4*)(Ar + kc * 32);
            float4 a1 = *(const float4*)(Ar + kc * 32 + 4);
            bf16x8 f;
            f[0] = (short)f2b(a0.x); f[1] = (short)f2b(a0.y);
            f[2] = (short)f2b(a0.z); f[3] = (short)f2b(a0.w);
            f[4] = (short)f2b(a1.x); f[5] = (short)f2b(a1.y);
            f[6] = (short)f2b(a1.z); f[7] = (short)f2b(a1.w);
            af[mt][kc] = f;
        }
    }

#pragma unroll
    for (int mat = 0; mat < 3; ++mat) {
        const unsigned short* W = (mat == 0) ? wk : (mat == 1) ? wv : wr;
#pragma unroll
        for (int nt = 0; nt < 4; ++nt) {
            const unsigned short* Wrow = W + (size_t)(n0 + nt * 16 + l16) * C_ + quad * 8;
            f32x4 acc[4];
#pragma unroll
            for (int mt = 0; mt < 4; ++mt) acc[mt] = (f32x4){0.f, 0.f, 0.f, 0.f};
#pragma unroll
            for (int kc = 0; kc < 8; ++kc) {
                bf16x8 bf = *(const bf16x8*)(Wrow + kc * 32);
#pragma unroll
                for (int mt = 0; mt < 4; ++mt)
                    acc[mt] = __builtin_amdgcn_mfma_f32_16x16x32_bf16(af[mt][kc], bf, acc[mt], 0, 0, 0);
            }
            const int col = n0 + nt * 16 + l16;
#pragma unroll
            for (int mt = 0; mt < 4; ++mt) {
#pragma unroll
                for (int i = 0; i < 4; ++i) {
                    const int row = m0 + mt * 16 + quad * 4 + i;
                    if (mat == 0) {
                        kout[(size_t)row * C_ + col] = acc[mt][i];
                    } else if (mat == 1) {
                        vout[(size_t)row * C_ + col] = acc[mt][i];
                    } else {
                        float s = 1.f / (1.f + __expf(-acc[mt][i]));
                        srout[(size_t)row * C_ + col] = f2b(s);
                    }
                }
            }
        }
    }
}

// ---------------- Final GEMM: out[m,n] = sum_k z[m,k]*Wo[n,k], f32 out --------
__global__ __launch_bounds__(256) void gemm_bt(const unsigned short* __restrict__ A,
                                               const unsigned short* __restrict__ W,
                                               float* __restrict__ Of) {
    const int wave = threadIdx.x >> 6, lane = threadIdx.x & 63;
    const int quad = lane >> 4, l16 = lane & 15;
    const int m0 = blockIdx.x * 64 + wave * 16;

    const unsigned short* Arow = A + (size_t)(m0 + l16) * C_ + quad * 8;
    bf16x8 af[8];
#pragma unroll
    for (int kc = 0; kc < 8; ++kc) af[kc] = *(const bf16x8*)(Arow + kc * 32);

    for (int nt = 0; nt < 16; ++nt) {
        const unsigned short* Wrow = W + (size_t)(nt * 16 + l16) * C_ + quad * 8;
        f32x4 acc = {0.f, 0.f, 0.f, 0.f};
#pragma unroll
        for (int kc = 0; kc < 8; ++kc) {
            bf16x8 bf = *(const bf16x8*)(Wrow + kc * 32);
            acc = __builtin_amdgcn_mfma_f32_16x16x32_bf16(af[kc], bf, acc, 0, 0, 0);
        }
        const int col = nt * 16 + l16;
#pragma unroll
        for (int i = 0; i < 4; ++i) {
            const int row = m0 + quad * 4 + i;
            Of[(size_t)row * C_ + col] = acc[i];
        }
    }
}

// ---------------- WKV pass 1: chunk-local states from zero init ----------------
__global__ __launch_bounds__(256) void wkv_pass1(const float* __restrict__ k,
                                                 const float* __restrict__ v,
                                                 const float* __restrict__ decay,
                                                 float* __restrict__ sp, float* __restrict__ sq,
                                                 float* __restrict__ so) {
    const int c = threadIdx.x, chunk = blockIdx.x, b = blockIdx.y;
    const float w = decay[c] * (1.0f / T_);
    size_t base = ((size_t)b * T_ + (size_t)chunk * L_) * C_ + c;
    float p = 0.f, q = 0.f, o = -1e38f;
    for (int t = 0; t < L_; t += 8) {
        float kk[8], vv[8];
#pragma unroll
        for (int j = 0; j < 8; ++j) {
            kk[j] = k[base + (size_t)(t + j) * C_];
            vv[j] = v[base + (size_t)(t + j) * C_];
        }
#pragma unroll
        for (int j = 0; j < 8; ++j) {
            float wo = w + o;
            float no = fmaxf(wo, kk[j]);
            float a2 = __expf(wo - no), b2 = __expf(kk[j] - no);
            p = a2 * p + b2 * vv[j];
            q = a2 * q + b2;
            o = no;
        }
    }
    size_t idx = ((size_t)b * NC_ + chunk) * C_ + c;
    sp[idx] = p; sq[idx] = q; so[idx] = o;
}

// ---------------- WKV combine: sequential over chunks, emit init states --------
__global__ __launch_bounds__(256) void wkv_combine(const float* __restrict__ decay,
                                                   const float* __restrict__ sp,
                                                   const float* __restrict__ sq,
                                                   const float* __restrict__ so,
                                                   float* __restrict__ pi, float* __restrict__ qi,
                                                   float* __restrict__ oi) {
    const int c = threadIdx.x, b = blockIdx.x;
    const float wL = decay[c] * (1.0f / T_) * (float)L_;
    float p = 0.f, q = 0.f, o = -1e38f;
    for (int ch = 0; ch < NC_; ch += 8) {
        float lp[8], lq[8], lo[8];
#pragma unroll
        for (int j = 0; j < 8; ++j) {
            size_t idx = ((size_t)b * NC_ + ch + j) * C_ + c;
            lp[j] = sp[idx]; lq[j] = sq[idx]; lo[j] = so[idx];
        }
#pragma unroll
        for (int j = 0; j < 8; ++j) {
            size_t idx = ((size_t)b * NC_ + ch + j) * C_ + c;
            pi[idx] = p; qi[idx] = q; oi[idx] = o;   // state BEFORE this chunk
            float ow = o + wL;
            float no = fmaxf(ow, lo[j]);
            float ea = __expf(ow - no), eb = __expf(lo[j] - no);
            p = ea * p + eb * lp[j];
            q = ea * q + eb * lq[j];
            o = no;
        }
    }
}

// ---------------- WKV pass 2 fused with LayerNorm + sigmoid gate ---------------
// Block = (chunk, b), 256 threads = one channel each. The block owns all 256
// channels of 64 consecutive timesteps -> LayerNorm done in-block via LDS
// transpose (wave w reduces rows 2w, 2w+1 of each 8-timestep tile).
__global__ __launch_bounds__(256) void wkv_pass2_ln(const float* __restrict__ k,
                                                    const float* __restrict__ v,
                                                    const unsigned short* __restrict__ sr,
                                                    const float* __restrict__ decay,
                                                    const float* __restrict__ first,
                                                    const float* __restrict__ lw,
                                                    const float* __restrict__ lb,
                                                    const float* __restrict__ pi,
                                                    const float* __restrict__ qi,
                                                    const float* __restrict__ oi,
                                                    unsigned short* __restrict__ z) {
    __shared__ float tile[8][260];          // 260 stride: float4-aligned rows
    __shared__ float mu_s[8], rs_s[8];
    const int c = threadIdx.x, chunk = blockIdx.x, b = blockIdx.y;
    const int wave = c >> 6, lane = c & 63;
    const float w = decay[c] * (1.0f / T_);
    const float u = first[c] * (1.0f / T_);
    const float gw = lw[c], gb = lb[c];
    size_t sidx = ((size_t)b * NC_ + chunk) * C_ + c;
    float p = pi[sidx], q = qi[sidx], o = oi[sidx];
    size_t base = ((size_t)b * T_ + (size_t)chunk * L_) * C_ + c;

    for (int t = 0; t < L_; t += 8) {
        float kk[8], vv[8], yy[8];
#pragma unroll
        for (int j = 0; j < 8; ++j) {
            kk[j] = k[base + (size_t)(t + j) * C_];
            vv[j] = v[base + (size_t)(t + j) * C_];
        }
#pragma unroll
        for (int j = 0; j < 8; ++j) {
            float uk = u + kk[j];
            float no = fmaxf(o, uk);
            float a = __expf(o - no), bb = __expf(uk - no);
            yy[j] = (a * p + bb * vv[j]) / (a * q + bb);
            float wo = w + o;
            float no2 = fmaxf(wo, kk[j]);
            float a2 = __expf(wo - no2), b2 = __expf(kk[j] - no2);
            p = a2 * p + b2 * vv[j];
            q = a2 * q + b2;
            o = no2;
        }
#pragma unroll
        for (int j = 0; j < 8; ++j) tile[j][c] = yy[j];
        __syncthreads();
#pragma unroll
        for (int r = 0; r < 2; ++r) {
            const int j = wave * 2 + r;
            float4 t4 = *(const float4*)&tile[j][lane * 4];
            float s = t4.x + t4.y + t4.z + t4.w;
            float ss = t4.x * t4.x + t4.y * t4.y + t4.z * t4.z + t4.w * t4.w;
#pragma unroll
            for (int m = 1; m < 64; m <<= 1) {
                s += __shfl_xor(s, m, 64);
                ss += __shfl_xor(ss, m, 64);
            }
            if (lane == 0) {
                float mu = s * (1.f / C_);
                mu_s[j] = mu;
                rs_s[j] = rsqrtf(ss * (1.f / C_) - mu * mu + 1e-5f);
            }
        }
        __syncthreads();
#pragma unroll
        for (int j = 0; j < 8; ++j) {
            float zz = (yy[j] - mu_s[j]) * rs_s[j] * gw + gb;
            zz *= b2f(sr[base + (size_t)(t + j) * C_]);
            z[base + (size_t)(t + j) * C_] = f2b(zz);
        }
    }
}

extern "C" void kernel_launch(void* const* d_in, const int* in_sizes, int n_in,
                              void* d_out, int out_size, void* d_ws, size_t ws_size,
                              hipStream_t stream) {
    const float* x     = (const float*)d_in[0];
    const float* Wk    = (const float*)d_in[1];
    const float* Wv    = (const float*)d_in[2];
    const float* Wr    = (const float*)d_in[3];
    const float* Wo    = (const float*)d_in[4];
    const float* decay = (const float*)d_in[5];
    const float* first = (const float*)d_in[6];
    const float* lnw   = (const float*)d_in[7];
    const float* lnb   = (const float*)d_in[8];
    float* out = (float*)d_out;

    char* ws = (char*)d_ws;
    const size_t NE = (size_t)M_ * C_;              // 8388608
    unsigned short* wkb = (unsigned short*)ws; ws += 65536 * 2;
    unsigned short* wvb = (unsigned short*)ws; ws += 65536 * 2;
    unsigned short* wrb = (unsigned short*)ws; ws += 65536 * 2;
    unsigned short* wob = (unsigned short*)ws; ws += 65536 * 2;
    float* kbuf = (float*)ws; ws += NE * 4;
    float* vbuf = (float*)ws; ws += NE * 4;
    unsigned short* srb = (unsigned short*)ws; ws += NE * 2;
    unsigned short* zb  = (unsigned short*)ws; ws += NE * 2;
    const size_t SE = (size_t)B_ * NC_ * C_;        // 131072
    float* sp = (float*)ws; ws += SE * 4;
    float* sq = (float*)ws; ws += SE * 4;
    float* so = (float*)ws; ws += SE * 4;
    float* pi = (float*)ws; ws += SE * 4;
    float* qi = (float*)ws; ws += SE * 4;
    float* oi = (float*)ws; ws += SE * 4;

    cvt_w<<<dim3(64, 4), 256, 0, stream>>>(Wk, Wv, Wr, Wo, wkb, wvb, wrb, wob);

    gemm_qkv<<<M_ / 64, 256, 0, stream>>>(x, wkb, wvb, wrb, kbuf, vbuf, srb);

    wkv_pass1<<<dim3(NC_, B_), 256, 0, stream>>>(kbuf, vbuf, decay, sp, sq, so);
    wkv_combine<<<B_, 256, 0, stream>>>(decay, sp, sq, so, pi, qi, oi);
    wkv_pass2_ln<<<dim3(NC_, B_), 256, 0, stream>>>(kbuf, vbuf, srb, decay, first,
                                                    lnw, lnb, pi, qi, oi, zb);

    gemm_bt<<<M_ / 64, 256, 0, stream>>>(zb, wob, out);
}